// Round 5
// baseline (272.097 us; speedup 1.0000x reference)
//
#include <hip/hip_runtime.h>
#include <hip/hip_bf16.h>
#include <stdint.h>

#define B_   2
#define T_   2048
#define CEMB 2048
#define H_   16
#define HKV_ 4
#define D_   128

typedef __attribute__((ext_vector_type(8))) short bf16x8;   // 8 x bf16 (4 VGPR)
typedef __attribute__((ext_vector_type(4))) float f32x4;    // MFMA 16x16 accumulator

#if __has_builtin(__builtin_amdgcn_exp2f)
#define EXP2(x) __builtin_amdgcn_exp2f(x)
#else
#define EXP2(x) exp2f(x)
#endif

__device__ __forceinline__ unsigned short f2b(float f) {
  union { float f; unsigned u; } v; v.f = f;
  unsigned r = v.u + 0x7FFFu + ((v.u >> 16) & 1u);   // RNE
  return (unsigned short)(r >> 16);
}
__device__ __forceinline__ float b2f(unsigned short u) {
  union { unsigned u; float f; } v; v.u = ((unsigned)u) << 16; return v.f;
}
// pack 2 f32 -> 2 bf16 (RNE), single instruction
__device__ __forceinline__ unsigned cvtpk(float lo, float hi) {
  unsigned r;
  asm("v_cvt_pk_bf16_f32 %0, %1, %2" : "=v"(r) : "v"(lo), "v"(hi));
  return r;
}

// async global->LDS, 16B per lane; LDS dest = wave-uniform base + lane*16
__device__ __forceinline__ void gl16(const void* g, void* l) {
  __builtin_amdgcn_global_load_lds(
      (const __attribute__((address_space(1))) unsigned int*)g,
      (__attribute__((address_space(3))) unsigned int*)l, 16, 0, 0);
}

#define FENCE() asm volatile("" ::: "memory")

// ---------------- f32 -> bf16 convert (vectorized) ----------------
__global__ void cvt_kernel(const float* __restrict__ src,
                           unsigned short* __restrict__ dst, int n4) {
  int i = blockIdx.x * blockDim.x + threadIdx.x;
  const int stride = gridDim.x * blockDim.x;
  for (; i < n4; i += stride) {
    float4 v = ((const float4*)src)[i];
    ushort4 o;
    o.x = f2b(v.x); o.y = f2b(v.y); o.z = f2b(v.z); o.w = f2b(v.w);
    ((ushort4*)dst)[i] = o;
  }
}

// ---------------- GEMM 256x256, 8-phase counted-vmcnt pipeline ---------------
// C[M][N] = A[M][K] (bf16) * W[N][K]^T (bf16).  8 waves, per-wave C = 128x64
// (fragment-interleaved: row frag = fr*2+wr, col frag = fc*4+wc).  K-tile = 64.
// LDS 128 KiB: As/Bs [2 dbuf][2 half][128][64].  Per phase: 12 ds_read_b128 +
// 1 half-tile stage (2 x global_load_lds w/ chunk^row&7 swizzled source) +
// 16 MFMA.  vmcnt(4) gate once per K-tile (2 half-tiles in flight).
__global__ __launch_bounds__(512, 2)
void gemm256(const unsigned short* __restrict__ A,
             const unsigned short* __restrict__ W,
             void* __restrict__ Cmat, int M, int N, int K, int obf16) {
  __shared__ alignas(16) unsigned short As[2][2][128][64];
  __shared__ alignas(16) unsigned short Bs[2][2][128][64];

  const int tid  = threadIdx.x;
  const int lane = tid & 63;
  const int w    = tid >> 6;         // wave 0..7
  const int wr   = w >> 2;           // M interleave bit
  const int wc   = w & 3;            // N interleave
  const int l16  = lane & 15, g4 = lane >> 4;
  const int srow = lane >> 3;        // staging row within 8-row group
  const int schk = lane & 7;         // staging 16B chunk

  // XCD-aware swizzle (both grids have nwg % 8 == 0)
  const int gx  = gridDim.x;
  const int nwg = gx * gridDim.y;
  const int lin = blockIdx.y * gx + blockIdx.x;
  const int cpx = nwg >> 3;
  const int swz = (lin & 7) * cpx + (lin >> 3);
  const int m0 = (swz / gx) * 256;
  const int n0 = (swz % gx) * 256;

  const unsigned short* Ap = A + (size_t)m0 * K;
  const unsigned short* Wp = W + (size_t)n0 * K;
  const int nk = K >> 6;

  f32x4 acc[8][4] = {};

  auto stA = [&](int ts, int h) {    // stage A half-tile (128 rows x 64 k)
    const unsigned short* g = Ap + (size_t)(h * 128 + w * 8 + srow) * K
                                 + ts * 64 + ((schk ^ srow) << 3);
    unsigned short* l = &As[ts & 1][h][w * 8][0];
    gl16(g, l);
    gl16(g + (size_t)64 * K, l + 64 * 64);
  };
  auto stB = [&](int ts, int h) {
    const unsigned short* g = Wp + (size_t)(h * 128 + w * 8 + srow) * K
                                 + ts * 64 + ((schk ^ srow) << 3);
    unsigned short* l = &Bs[ts & 1][h][w * 8][0];
    gl16(g, l);
    gl16(g + (size_t)64 * K, l + 64 * 64);
  };

  // prologue: stream halves 0..5 = tile0 {A0,B0,A1,B1} + tile1 {A0,B0}
  stA(0, 0); stB(0, 0); stA(0, 1); stB(0, 1);
  stA(1, 0); stB(1, 0);
  asm volatile("s_waitcnt vmcnt(4)" ::: "memory");   // tile0 fully landed
  __builtin_amdgcn_s_barrier();
  FENCE();

  for (int tau = 0; tau < nk; ++tau) {
    const int buf = tau & 1;
    #pragma unroll
    for (int q = 0; q < 4; ++q) {
      const int ha = q >> 1, hb = q & 1;   // quadrant -> (A half, B half)
      // --- ds-read this quadrant's fragments (8 A + 4 B b128, swizzled)
      bf16x8 af[4][2], bfr[2][2];
      #pragma unroll
      for (int mi = 0; mi < 4; ++mi) {
        const int har = (mi * 2 + wr) * 16 + l16;
        #pragma unroll
        for (int ks = 0; ks < 2; ++ks)
          af[mi][ks] = *(const bf16x8*)&As[buf][ha][har][((ks * 4 + g4) ^ (l16 & 7)) << 3];
      }
      #pragma unroll
      for (int ni = 0; ni < 2; ++ni) {
        const int hbr = (ni * 4 + wc) * 16 + l16;
        #pragma unroll
        for (int ks = 0; ks < 2; ++ks)
          bfr[ni][ks] = *(const bf16x8*)&Bs[buf][hb][hbr][((ks * 4 + g4) ^ (l16 & 7)) << 3];
      }
      // --- stage one half-tile (stream j = 4*tau + q + 6); region-death safe:
      //  q0: A1 of tau+1 (prev reader ended at (tau-1,q3) barrier)
      //  q1: B1 of tau+1 | q2: A0 of tau+2 (this tau's A0 dead after q1)
      //  q3: B0 of tau+2 (this tau's B0 dead after q2)
      if (q == 0)      { if (tau + 1 < nk) stA(tau + 1, 1); }
      else if (q == 1) { if (tau + 1 < nk) stB(tau + 1, 1); }
      else if (q == 2) { if (tau + 2 < nk) stA(tau + 2, 0); }
      else             { if (tau + 2 < nk) stB(tau + 2, 0); }
      // --- compute phase
      __builtin_amdgcn_s_barrier();
      asm volatile("s_waitcnt lgkmcnt(0)" ::: "memory");  // pin+drain ds_reads
      __builtin_amdgcn_s_setprio(1);
      #pragma unroll
      for (int mi = 0; mi < 4; ++mi) {
        #pragma unroll
        for (int ni = 0; ni < 2; ++ni) {
          f32x4 t = acc[ha * 4 + mi][hb * 2 + ni];
          t = __builtin_amdgcn_mfma_f32_16x16x32_bf16(af[mi][0], bfr[ni][0], t, 0, 0, 0);
          t = __builtin_amdgcn_mfma_f32_16x16x32_bf16(af[mi][1], bfr[ni][1], t, 0, 0, 0);
          acc[ha * 4 + mi][hb * 2 + ni] = t;
        }
      }
      __builtin_amdgcn_s_setprio(0);
      if (q == 3) {    // K-tile gate: tau+1's 4 halves landed (last 2 stages may fly)
        if (tau + 2 < nk) asm volatile("s_waitcnt vmcnt(4)" ::: "memory");
        else              asm volatile("s_waitcnt vmcnt(0)" ::: "memory");
      }
      __builtin_amdgcn_s_barrier();
      FENCE();
    }
  }

  // epilogue: C/D layout col = lane&15, row = (lane>>4)*4 + reg
  #pragma unroll
  for (int fr = 0; fr < 8; ++fr) {
    #pragma unroll
    for (int fc = 0; fc < 4; ++fc) {
      const int row = m0 + (fr * 2 + wr) * 16 + g4 * 4;
      const int col = n0 + (fc * 4 + wc) * 16 + l16;
      if (obf16) {
        unsigned short* Cb = (unsigned short*)Cmat;
        #pragma unroll
        for (int r = 0; r < 4; ++r)
          Cb[(size_t)(row + r) * N + col] = f2b(acc[fr][fc][r]);
      } else {
        float* Cf = (float*)Cmat;
        #pragma unroll
        for (int r = 0; r < 4; ++r)
          Cf[(size_t)(row + r) * N + col] = acc[fr][fc][r];
      }
    }
  }
}

// ---------------- fused RoPE + RMSNorm (bf16 in) + [B,H,T,D] bf16 out --------
__global__ __launch_bounds__(128)
void rope_norm(const unsigned short* __restrict__ X, int rstride,
               const float* __restrict__ Cos, const float* __restrict__ Sin,
               unsigned short* __restrict__ Out, int Hn, float out_scale) {
  const int idx = blockIdx.x;
  const int h  = idx % Hn;
  const int bt = idx / Hn;
  const int t  = bt & (T_ - 1);
  const int b  = bt >> 11;
  const int d  = threadIdx.x;        // 0..127
  const unsigned short* src = X + (size_t)bt * rstride + h * D_;
  float y;
  if (d < 64) {
    float x1 = b2f(src[d]), x2 = b2f(src[d + 64]);
    float c = Cos[t * 64 + d], s = Sin[t * 64 + d];
    y = x1 * c + x2 * s;
  } else {
    int dd = d - 64;
    float x1 = b2f(src[dd]), x2 = b2f(src[d]);
    float c = Cos[t * 64 + dd], s = Sin[t * 64 + dd];
    y = -x1 * s + x2 * c;
  }
  float ss = y * y;
  #pragma unroll
  for (int m = 32; m; m >>= 1) ss += __shfl_xor(ss, m);
  __shared__ float red[2];
  if ((d & 63) == 0) red[d >> 6] = ss;
  __syncthreads();
  const float tot  = red[0] + red[1];
  const float rinv = rsqrtf(tot * (1.0f / 128.0f) + 1.1920929e-7f) * out_scale;
  Out[(((size_t)b * Hn + h) * T_ + t) * D_ + d] = f2b(y * rinv);
}

// ---------------- V: [B,T,*,D] bf16 (strided) -> [B,HKV,D,T] bf16 ------------
__global__ __launch_bounds__(256)
void vtrans(const unsigned short* __restrict__ Vf, int rstride,
            unsigned short* __restrict__ Vt) {
  __shared__ float tile[32][65];
  const int t0 = blockIdx.x * 64;
  const int d0 = blockIdx.y * 32;
  const int bh = blockIdx.z;
  const int b = bh >> 2, hk = bh & 3;
  const int tid = threadIdx.x;
  {
    const int di = tid & 31, ts = tid >> 5;
    #pragma unroll
    for (int i = 0; i < 8; ++i) {
      int tt = ts + i * 8;
      tile[di][tt] = b2f(Vf[(size_t)(b * T_ + t0 + tt) * rstride + hk * D_ + d0 + di]);
    }
  }
  __syncthreads();
  {
    const int ti = tid & 63, ds = tid >> 6;
    #pragma unroll
    for (int i = 0; i < 8; ++i) {
      int dd = ds * 8 + i;
      Vt[((size_t)bh * D_ + d0 + dd) * T_ + t0 + ti] = f2b(tile[dd][ti]);
    }
  }
}

// ---------------- flash attention, causal, 4-wave cooperative ----------------
// Pair-balanced: block processes q-tiles {15-p, p} sequentially = 34 tile-iters
// for every block. Fixed-shift softmax (RMSNorm bound |score*log2e| <= 16.33):
// P = exp2(S'), no max tracking, no rescale; l is a per-lane partial sum.
#define KVB 64

__global__ __launch_bounds__(256)
void attn_kernel(const unsigned short* __restrict__ Qn,
                 const unsigned short* __restrict__ Kn,
                 const unsigned short* __restrict__ Vt,
                 unsigned short* __restrict__ Yb) {
  __shared__ alignas(16) unsigned short Ks[2][KVB * D_];   // [key][chunk^(key&7)]
  __shared__ alignas(16) unsigned short Vs[2][D_ * KVB];   // V^T [d][chunk^(d&7)]
  __shared__ alignas(16) unsigned short plds[4 * 2 * 16 * 64];

  const int tid = threadIdx.x;
  const int lane = tid & 63;
  const int w = tid >> 6;
  const int l16 = lane & 15, g4 = lane >> 4;
  const int bh = blockIdx.x;              // bh-major: XCD KV working set = 4MB
  const int pr = blockIdx.y;              // pair index 0..7
  const int b = bh >> 4, h = bh & 15;
  const int hk = h >> 2;                  // GQA: 4 q-heads per kv-head

  const unsigned short* kp = Kn + ((size_t)(b * HKV_ + hk) * T_) * D_;
  const unsigned short* vp = Vt + ((size_t)(b * HKV_ + hk) * D_) * T_;
  unsigned short* pw = plds + w * 2048;   // per-wave P region

  // staging lane decomposition
  const int kr4 = lane >> 4, kc = lane & 15;   // K: 4 rows (256B) per instr
  const int vr8 = lane >> 3, vc = lane & 7;    // V: 8 rows (128B) per instr

  for (int pass = 0; pass < 2; ++pass) {
    const int qt = pass ? pr : 15 - pr;        // heavy tile first
    const int t0 = qt * 128;
    const int qrow0 = t0 + w * 32;
    const int qmax = qrow0 + 31;
    const int nt = qt * 2 + 2;

    const unsigned short* qp = Qn + ((size_t)bh * T_ + qrow0) * D_;
    bf16x8 qf[2][4];
    #pragma unroll
    for (int qi = 0; qi < 2; ++qi)
      #pragma unroll
      for (int kq = 0; kq < 4; ++kq)
        qf[qi][kq] = *(const bf16x8*)(qp + (size_t)(qi * 16 + l16) * D_ + kq * 32 + g4 * 8);

    f32x4 o[2][8] = {};
    float l_part[2] = {0.f, 0.f};

    // prologue: stage tile 0 into buf 0 (safe: buf0 not read by prev pass tail)
    {
      #pragma unroll
      for (int j = 0; j < 4; ++j) {
        int key = w * 16 + j * 4 + kr4;
        int cg = kc ^ (key & 7);
        gl16(kp + (size_t)key * D_ + cg * 8, &Ks[0][(w * 16 + j * 4) * D_]);
      }
      #pragma unroll
      for (int j = 0; j < 4; ++j) {
        int d = w * 32 + j * 8 + vr8;
        int cg = vc ^ (d & 7);
        gl16(vp + (size_t)d * T_ + cg * 8, &Vs[0][(w * 32 + j * 8) * KVB]);
      }
    }

    for (int t = 0; t < nt; ++t) {
      __syncthreads();   // drains vmcnt(0): buf[t&1] staged; prev compute done
      if (t + 1 < nt) {  // stage next tile into other buffer
        const int kv1 = (t + 1) * KVB;
        #pragma unroll
        for (int j = 0; j < 4; ++j) {
          int key = w * 16 + j * 4 + kr4;
          int cg = kc ^ (key & 7);
          gl16(kp + (size_t)(kv1 + key) * D_ + cg * 8, &Ks[(t + 1) & 1][(w * 16 + j * 4) * D_]);
        }
        #pragma unroll
        for (int j = 0; j < 4; ++j) {
          int d = w * 32 + j * 8 + vr8;
          int cg = vc ^ (d & 7);
          gl16(vp + (size_t)d * T_ + kv1 + cg * 8, &Vs[(t + 1) & 1][(w * 32 + j * 8) * KVB]);
        }
      }
      const int kv0 = t * KVB;
      if (kv0 <= qmax) {
        const unsigned short* kb = Ks[t & 1];
        const unsigned short* vb = Vs[t & 1];
        // S^T[key][q] = sum_d K[key][d]*Q[q][d]
        f32x4 sacc[2][4] = {};
        #pragma unroll
        for (int ss = 0; ss < 4; ++ss) {
          const int key = ss * 16 + l16;
          bf16x8 kf[4];
          #pragma unroll
          for (int kq = 0; kq < 4; ++kq) {
            int sc = (kq * 4 + g4) ^ (key & 7);
            kf[kq] = *(const bf16x8*)(kb + key * D_ + sc * 8);
          }
          #pragma unroll
          for (int qi = 0; qi < 2; ++qi)
            #pragma unroll
            for (int kq = 0; kq < 4; ++kq)
              sacc[qi][ss] = __builtin_amdgcn_mfma_f32_16x16x32_bf16(
                  kf[kq], qf[qi][kq], sacc[qi][ss], 0, 0, 0);
        }
        const bool need_mask = (kv0 + KVB - 1 > qrow0);
        #pragma unroll
        for (int qi = 0; qi < 2; ++qi) {
          const int qglob = qrow0 + qi * 16 + l16;
          float p[16];
          float ls = 0.f;
          #pragma unroll
          for (int ss = 0; ss < 4; ++ss) {
            #pragma unroll
            for (int r = 0; r < 4; ++r) {
              float e = EXP2(sacc[qi][ss][r]);   // bounded: |arg| <= 16.33
              if (need_mask) {
                int key = kv0 + ss * 16 + g4 * 4 + r;
                e = (key <= qglob) ? e : 0.f;
              }
              p[ss * 4 + r] = e;
              ls += e;
            }
          }
          l_part[qi] += ls;
          // P[q][key] -> per-wave LDS, swizzled 16B chunks: sc = ch ^ (row&7)
          #pragma unroll
          for (int ss = 0; ss < 4; ++ss) {
            uint2 u;
            u.x = cvtpk(p[ss * 4 + 0], p[ss * 4 + 1]);
            u.y = cvtpk(p[ss * 4 + 2], p[ss * 4 + 3]);
            int ch = ss * 2 + (g4 >> 1);
            int sc = ch ^ (l16 & 7);
            *(uint2*)&pw[qi * 1024 + l16 * 64 + sc * 8 + (g4 & 1) * 4] = u;
          }
        }
        // PV: O^T[d][q] += sum_key V^T[d][key] * P[q][key]
        bf16x8 pf[2][2];
        #pragma unroll
        for (int qi = 0; qi < 2; ++qi)
          #pragma unroll
          for (int ks = 0; ks < 2; ++ks) {
            int sc = (ks * 4 + g4) ^ (l16 & 7);
            pf[qi][ks] = *(const bf16x8*)&pw[qi * 1024 + l16 * 64 + sc * 8];
          }
        #pragma unroll
        for (int dt = 0; dt < 8; ++dt) {
          const int d = dt * 16 + l16;
          int sc0 = (0 * 4 + g4) ^ (d & 7);
          int sc1 = (1 * 4 + g4) ^ (d & 7);
          bf16x8 vf0 = *(const bf16x8*)(vb + d * KVB + sc0 * 8);
          bf16x8 vf1 = *(const bf16x8*)(vb + d * KVB + sc1 * 8);
          #pragma unroll
          for (int qi = 0; qi < 2; ++qi) {
            o[qi][dt] = __builtin_amdgcn_mfma_f32_16x16x32_bf16(vf0, pf[qi][0], o[qi][dt], 0, 0, 0);
            o[qi][dt] = __builtin_amdgcn_mfma_f32_16x16x32_bf16(vf1, pf[qi][1], o[qi][dt], 0, 0, 0);
          }
        }
      }
    }

    #pragma unroll
    for (int qi = 0; qi < 2; ++qi) {
      float lsum = l_part[qi];
      lsum += __shfl_xor(lsum, 16);
      lsum += __shfl_xor(lsum, 32);
      const float inv_l = 1.0f / lsum;
      unsigned short* yrow = Yb + ((size_t)(b * T_ + qrow0 + qi * 16 + l16) * CEMB) + h * D_;
      #pragma unroll
      for (int dt = 0; dt < 8; ++dt) {
        uint2 u;
        u.x = cvtpk(o[qi][dt][0] * inv_l, o[qi][dt][1] * inv_l);
        u.y = cvtpk(o[qi][dt][2] * inv_l, o[qi][dt][3] * inv_l);
        *(uint2*)(yrow + dt * 16 + g4 * 4) = u;
      }
    }
  }
}

// ---------------------------------------------------------------------------
extern "C" void kernel_launch(void* const* d_in, const int* in_sizes, int n_in,
                              void* d_out, int out_size, void* d_ws, size_t ws_size,
                              hipStream_t stream) {
  const float* x    = (const float*)d_in[0];
  const float* cosp = (const float*)d_in[1];
  const float* sinp = (const float*)d_in[2];
  const float* Wq   = (const float*)d_in[3];
  const float* Wk   = (const float*)d_in[4];
  const float* Wv   = (const float*)d_in[5];
  const float* Wo   = (const float*)d_in[6];
  float* out = (float*)d_out;

  char* ws = (char*)d_ws;
  size_t off = 0;
  auto alloc = [&](size_t bytes) {
    void* p = ws + off;
    off += (bytes + 255) & ~(size_t)255;
    return p;
  };
  const size_t MT = (size_t)B_ * T_;  // 4096
  const int NQKV = 3072;              // 2048 q + 512 k + 512 v
  unsigned short* xb    = (unsigned short*)alloc(MT * CEMB * 2);
  unsigned short* wqkvb = (unsigned short*)alloc((size_t)NQKV * 2048 * 2);
  unsigned short* wob   = (unsigned short*)alloc((size_t)2048 * 2048 * 2);
  unsigned short* qkvb  = (unsigned short*)alloc(MT * NQKV * 2);
  unsigned short* qn    = (unsigned short*)alloc((size_t)B_ * H_ * T_ * D_ * 2);
  unsigned short* kn    = (unsigned short*)alloc((size_t)B_ * HKV_ * T_ * D_ * 2);
  unsigned short* vt    = (unsigned short*)alloc((size_t)B_ * HKV_ * D_ * T_ * 2);
  unsigned short* yb    = (unsigned short*)alloc(MT * CEMB * 2);

  // bf16 casts (weights concatenated into [3072][2048])
  cvt_kernel<<<2048, 256, 0, stream>>>(x,  xb, (int)(MT * CEMB / 4));
  cvt_kernel<<<1024, 256, 0, stream>>>(Wq, wqkvb,                2048 * 2048 / 4);
  cvt_kernel<<<256,  256, 0, stream>>>(Wk, wqkvb + 2048 * 2048,  512 * 2048 / 4);
  cvt_kernel<<<256,  256, 0, stream>>>(Wv, wqkvb + 2560 * 2048,  512 * 2048 / 4);
  cvt_kernel<<<1024, 256, 0, stream>>>(Wo, wob,                  2048 * 2048 / 4);

  // fused QKV projection: [4096][3072] bf16  (grid 12x16 = 192 blocks)
  gemm256<<<dim3(NQKV / 256, 4096 / 256), 512, 0, stream>>>(xb, wqkvb, qkvb, 4096, NQKV, 2048, 1);

  // RoPE + RMSNorm; Q gets (1/sqrt(D))*log2(e) folded (softmax in exp2 domain)
  rope_norm<<<4096 * H_,   128, 0, stream>>>(qkvb,        NQKV, cosp, sinp, qn, H_,   0.1275174324f);
  rope_norm<<<4096 * HKV_, 128, 0, stream>>>(qkvb + 2048, NQKV, cosp, sinp, kn, HKV_, 1.0f);
  vtrans<<<dim3(T_ / 64, D_ / 32, B_ * HKV_), 256, 0, stream>>>(qkvb + 2560, NQKV, vt);

  // causal flash attention: pair-balanced blocks (34 tile-iters each)
  attn_kernel<<<dim3(B_ * H_, 8), 256, 0, stream>>>(qn, kn, vt, yb);

  // output projection -> f32 d_out  (grid 8x16 = 128 blocks)
  gemm256<<<dim3(2048 / 256, 4096 / 256), 512, 0, stream>>>(yb, wob, out, 4096, 2048, 2048, 0);
}

// Round 6
// 256.143 us; speedup vs baseline: 1.0623x; 1.0623x over previous
//
#include <hip/hip_runtime.h>
#include <hip/hip_bf16.h>
#include <stdint.h>

#define B_   2
#define T_   2048
#define CEMB 2048
#define H_   16
#define HKV_ 4
#define D_   128

typedef __attribute__((ext_vector_type(8))) short bf16x8;   // 8 x bf16 (4 VGPR)
typedef __attribute__((ext_vector_type(4))) float f32x4;    // MFMA 16x16 accumulator

#if __has_builtin(__builtin_amdgcn_exp2f)
#define EXP2(x) __builtin_amdgcn_exp2f(x)
#else
#define EXP2(x) exp2f(x)
#endif

__device__ __forceinline__ unsigned short f2b(float f) {
  union { float f; unsigned u; } v; v.f = f;
  unsigned r = v.u + 0x7FFFu + ((v.u >> 16) & 1u);   // RNE
  return (unsigned short)(r >> 16);
}
__device__ __forceinline__ float b2f(unsigned short u) {
  union { unsigned u; float f; } v; v.u = ((unsigned)u) << 16; return v.f;
}
// pack 2 f32 -> 2 bf16 (RNE), single instruction
__device__ __forceinline__ unsigned cvtpk(float lo, float hi) {
  unsigned r;
  asm("v_cvt_pk_bf16_f32 %0, %1, %2" : "=v"(r) : "v"(lo), "v"(hi));
  return r;
}

// async global->LDS, 16B per lane; LDS dest = wave-uniform base + lane*16
__device__ __forceinline__ void gl16(const void* g, void* l) {
  __builtin_amdgcn_global_load_lds(
      (const __attribute__((address_space(1))) unsigned int*)g,
      (__attribute__((address_space(3))) unsigned int*)l, 16, 0, 0);
}

#define FENCE() asm volatile("" ::: "memory")

// ---------------- f32 -> bf16 convert (vectorized) ----------------
__global__ void cvt_kernel(const float* __restrict__ src,
                           unsigned short* __restrict__ dst, int n4) {
  int i = blockIdx.x * blockDim.x + threadIdx.x;
  const int stride = gridDim.x * blockDim.x;
  for (; i < n4; i += stride) {
    float4 v = ((const float4*)src)[i];
    ushort4 o;
    o.x = f2b(v.x); o.y = f2b(v.y); o.z = f2b(v.z); o.w = f2b(v.w);
    ((ushort4*)dst)[i] = o;
  }
}

// ---------------- GEMM 256x256, 8-phase counted-vmcnt pipeline ---------------
// C[M][N] = A[M][K] (bf16) * W[N][K]^T (bf16).  8 waves, per-wave C = 128x64
// (fragment-interleaved: row frag = fr*2+wr, col frag = fc*4+wc).  K-tile = 64.
// ha-major phase order: A-fragments loaded once per half and held in registers
// across the hb=0 phase barrier -> 32 ds_read_b128 per K-tile (was 48),
// making the kernel MFMA-bound (LDS 2048 cyc < MFMA 2483 cyc per K-tile).
__global__ __launch_bounds__(512, 2)
void gemm256(const unsigned short* __restrict__ A,
             const unsigned short* __restrict__ W,
             void* __restrict__ Cmat, int M, int N, int K, int obf16) {
  __shared__ alignas(16) unsigned short As[2][2][128][64];
  __shared__ alignas(16) unsigned short Bs[2][2][128][64];

  const int tid  = threadIdx.x;
  const int lane = tid & 63;
  const int w    = tid >> 6;         // wave 0..7
  const int wr   = w >> 2;           // M interleave bit
  const int wc   = w & 3;            // N interleave
  const int l16  = lane & 15, g4 = lane >> 4;
  const int srow = lane >> 3;        // staging row within 8-row group
  const int schk = lane & 7;         // staging 16B chunk

  // XCD-aware swizzle (both grids have nwg % 8 == 0)
  const int gx  = gridDim.x;
  const int nwg = gx * gridDim.y;
  const int lin = blockIdx.y * gx + blockIdx.x;
  const int cpx = nwg >> 3;
  const int swz = (lin & 7) * cpx + (lin >> 3);
  const int m0 = (swz / gx) * 256;
  const int n0 = (swz % gx) * 256;

  const unsigned short* Ap = A + (size_t)m0 * K;
  const unsigned short* Wp = W + (size_t)n0 * K;
  const int nk = K >> 6;

  f32x4 acc[8][4] = {};

  auto stA = [&](int ts, int h) {    // stage A half-tile (128 rows x 64 k)
    const unsigned short* g = Ap + (size_t)(h * 128 + w * 8 + srow) * K
                                 + ts * 64 + ((schk ^ srow) << 3);
    unsigned short* l = &As[ts & 1][h][w * 8][0];
    gl16(g, l);
    gl16(g + (size_t)64 * K, l + 64 * 64);
  };
  auto stB = [&](int ts, int h) {
    const unsigned short* g = Wp + (size_t)(h * 128 + w * 8 + srow) * K
                                 + ts * 64 + ((schk ^ srow) << 3);
    unsigned short* l = &Bs[ts & 1][h][w * 8][0];
    gl16(g, l);
    gl16(g + (size_t)64 * K, l + 64 * 64);
  };

  // prologue: stream halves 0..5 = tile0 {A0,B0,A1,B1} + tile1 {A0,B0}
  stA(0, 0); stB(0, 0); stA(0, 1); stB(0, 1);
  stA(1, 0); stB(1, 0);
  asm volatile("s_waitcnt vmcnt(4)" ::: "memory");   // tile0 fully landed
  __builtin_amdgcn_s_barrier();
  FENCE();

  for (int tau = 0; tau < nk; ++tau) {
    const int buf = tau & 1;
    #pragma unroll
    for (int ha = 0; ha < 2; ++ha) {
      // ===== phase P0 (quadrant ha,hb=0): load af[ha] (8) + bfr0 (4) =====
      bf16x8 af[4][2], bfr[2][2];
      #pragma unroll
      for (int mi = 0; mi < 4; ++mi) {
        const int har = (mi * 2 + wr) * 16 + l16;
        #pragma unroll
        for (int ks = 0; ks < 2; ++ks)
          af[mi][ks] = *(const bf16x8*)&As[buf][ha][har][((ks * 4 + g4) ^ (l16 & 7)) << 3];
      }
      #pragma unroll
      for (int ni = 0; ni < 2; ++ni) {
        const int hbr = (ni * 4 + wc) * 16 + l16;
        #pragma unroll
        for (int ks = 0; ks < 2; ++ks)
          bfr[ni][ks] = *(const bf16x8*)&Bs[buf][0][hbr][((ks * 4 + g4) ^ (l16 & 7)) << 3];
      }
      // stage stream order preserved from validated R5 schedule
      if (ha == 0) { if (tau + 1 < nk) stA(tau + 1, 1); }
      else         { if (tau + 2 < nk) stA(tau + 2, 0); }
      __builtin_amdgcn_s_barrier();
      asm volatile("s_waitcnt lgkmcnt(0)" ::: "memory");
      __builtin_amdgcn_s_setprio(1);
      #pragma unroll
      for (int mi = 0; mi < 4; ++mi) {
        #pragma unroll
        for (int ni = 0; ni < 2; ++ni) {
          f32x4 t = acc[ha * 4 + mi][ni];
          t = __builtin_amdgcn_mfma_f32_16x16x32_bf16(af[mi][0], bfr[ni][0], t, 0, 0, 0);
          t = __builtin_amdgcn_mfma_f32_16x16x32_bf16(af[mi][1], bfr[ni][1], t, 0, 0, 0);
          acc[ha * 4 + mi][ni] = t;
        }
      }
      __builtin_amdgcn_s_setprio(0);
      __builtin_amdgcn_s_barrier();
      FENCE();
      // ===== phase P1 (quadrant ha,hb=1): load bfr1 only (4); af reused =====
      #pragma unroll
      for (int ni = 0; ni < 2; ++ni) {
        const int hbr = (ni * 4 + wc) * 16 + l16;
        #pragma unroll
        for (int ks = 0; ks < 2; ++ks)
          bfr[ni][ks] = *(const bf16x8*)&Bs[buf][1][hbr][((ks * 4 + g4) ^ (l16 & 7)) << 3];
      }
      if (ha == 0) { if (tau + 1 < nk) stB(tau + 1, 1); }
      else         { if (tau + 2 < nk) stB(tau + 2, 0); }
      __builtin_amdgcn_s_barrier();
      asm volatile("s_waitcnt lgkmcnt(0)" ::: "memory");
      __builtin_amdgcn_s_setprio(1);
      #pragma unroll
      for (int mi = 0; mi < 4; ++mi) {
        #pragma unroll
        for (int ni = 0; ni < 2; ++ni) {
          f32x4 t = acc[ha * 4 + mi][2 + ni];
          t = __builtin_amdgcn_mfma_f32_16x16x32_bf16(af[mi][0], bfr[ni][0], t, 0, 0, 0);
          t = __builtin_amdgcn_mfma_f32_16x16x32_bf16(af[mi][1], bfr[ni][1], t, 0, 0, 0);
          acc[ha * 4 + mi][2 + ni] = t;
        }
      }
      __builtin_amdgcn_s_setprio(0);
      if (ha == 1) {   // K-tile gate: tile tau+1's 4 halves landed
        if (tau + 2 < nk) asm volatile("s_waitcnt vmcnt(4)" ::: "memory");
        else              asm volatile("s_waitcnt vmcnt(0)" ::: "memory");
      }
      __builtin_amdgcn_s_barrier();
      FENCE();
    }
  }

  // epilogue: C/D layout col = lane&15, row = (lane>>4)*4 + reg
  #pragma unroll
  for (int fr = 0; fr < 8; ++fr) {
    #pragma unroll
    for (int fc = 0; fc < 4; ++fc) {
      const int row = m0 + (fr * 2 + wr) * 16 + g4 * 4;
      const int col = n0 + (fc * 4 + wc) * 16 + l16;
      if (obf16) {
        unsigned short* Cb = (unsigned short*)Cmat;
        #pragma unroll
        for (int r = 0; r < 4; ++r)
          Cb[(size_t)(row + r) * N + col] = f2b(acc[fr][fc][r]);
      } else {
        float* Cf = (float*)Cmat;
        #pragma unroll
        for (int r = 0; r < 4; ++r)
          Cf[(size_t)(row + r) * N + col] = acc[fr][fc][r];
      }
    }
  }
}

// ---------------- fused RoPE + RMSNorm (bf16 in) + [B,H,T,D] bf16 out --------
__global__ __launch_bounds__(128)
void rope_norm(const unsigned short* __restrict__ X, int rstride,
               const float* __restrict__ Cos, const float* __restrict__ Sin,
               unsigned short* __restrict__ Out, int Hn, float out_scale) {
  const int idx = blockIdx.x;
  const int h  = idx % Hn;
  const int bt = idx / Hn;
  const int t  = bt & (T_ - 1);
  const int b  = bt >> 11;
  const int d  = threadIdx.x;        // 0..127
  const unsigned short* src = X + (size_t)bt * rstride + h * D_;
  float y;
  if (d < 64) {
    float x1 = b2f(src[d]), x2 = b2f(src[d + 64]);
    float c = Cos[t * 64 + d], s = Sin[t * 64 + d];
    y = x1 * c + x2 * s;
  } else {
    int dd = d - 64;
    float x1 = b2f(src[dd]), x2 = b2f(src[d]);
    float c = Cos[t * 64 + dd], s = Sin[t * 64 + dd];
    y = -x1 * s + x2 * c;
  }
  float ss = y * y;
  #pragma unroll
  for (int m = 32; m; m >>= 1) ss += __shfl_xor(ss, m);
  __shared__ float red[2];
  if ((d & 63) == 0) red[d >> 6] = ss;
  __syncthreads();
  const float tot  = red[0] + red[1];
  const float rinv = rsqrtf(tot * (1.0f / 128.0f) + 1.1920929e-7f) * out_scale;
  Out[(((size_t)b * Hn + h) * T_ + t) * D_ + d] = f2b(y * rinv);
}

// ---------------- V: [B,T,*,D] bf16 (strided) -> [B,HKV,D,T] bf16 ------------
__global__ __launch_bounds__(256)
void vtrans(const unsigned short* __restrict__ Vf, int rstride,
            unsigned short* __restrict__ Vt) {
  __shared__ float tile[32][65];
  const int t0 = blockIdx.x * 64;
  const int d0 = blockIdx.y * 32;
  const int bh = blockIdx.z;
  const int b = bh >> 2, hk = bh & 3;
  const int tid = threadIdx.x;
  {
    const int di = tid & 31, ts = tid >> 5;
    #pragma unroll
    for (int i = 0; i < 8; ++i) {
      int tt = ts + i * 8;
      tile[di][tt] = b2f(Vf[(size_t)(b * T_ + t0 + tt) * rstride + hk * D_ + d0 + di]);
    }
  }
  __syncthreads();
  {
    const int ti = tid & 63, ds = tid >> 6;
    #pragma unroll
    for (int i = 0; i < 8; ++i) {
      int dd = ds * 8 + i;
      Vt[((size_t)bh * D_ + d0 + dd) * T_ + t0 + ti] = f2b(tile[dd][ti]);
    }
  }
}

// ---------------- flash attention, causal, 4-wave cooperative ----------------
// One q-tile (128 rows) per block; grid 32 bh x 16 qt with complementary
// mapping qt = by<8 ? by : 23-by so co-resident blocks (c, c+256) sum to 34
// tile-iters.  LDS 72 KB -> 2 blocks/CU (2 waves/SIMD: cross-block MFMA/VALU
// overlap).  Fixed-shift softmax (RMSNorm bound |score*log2e| <= 16.33).
#define KVB 64

__global__ __launch_bounds__(256)
void attn_kernel(const unsigned short* __restrict__ Qn,
                 const unsigned short* __restrict__ Kn,
                 const unsigned short* __restrict__ Vt,
                 unsigned short* __restrict__ Yb) {
  __shared__ alignas(16) unsigned short Ks[2][KVB * D_];   // [key][chunk^(key&7)]
  __shared__ alignas(16) unsigned short Vs[2][D_ * KVB];   // V^T [d][chunk^(d&7)]
  __shared__ alignas(16) unsigned short plds[4 * 16 * 64]; // per-wave 1KB, reused per qi

  const int tid = threadIdx.x;
  const int lane = tid & 63;
  const int w = tid >> 6;
  const int l16 = lane & 15, g4 = lane >> 4;
  const int bh = blockIdx.x;              // bh-major: XCD KV working set = 4MB
  const int by = blockIdx.y;
  const int qt = (by < 8) ? by : 23 - by; // complementary halves
  const int b = bh >> 4, h = bh & 15;
  const int hk = h >> 2;                  // GQA: 4 q-heads per kv-head

  const unsigned short* kp = Kn + ((size_t)(b * HKV_ + hk) * T_) * D_;
  const unsigned short* vp = Vt + ((size_t)(b * HKV_ + hk) * D_) * T_;
  unsigned short* pw = plds + w * 1024;   // per-wave P region

  // staging lane decomposition
  const int kr4 = lane >> 4, kc = lane & 15;   // K: 4 rows (256B) per instr
  const int vr8 = lane >> 3, vc = lane & 7;    // V: 8 rows (128B) per instr

  const int t0 = qt * 128;
  const int qrow0 = t0 + w * 32;
  const int qmax = qrow0 + 31;
  const int nt = qt * 2 + 2;

  const unsigned short* qp = Qn + ((size_t)bh * T_ + qrow0) * D_;
  bf16x8 qf[2][4];
  #pragma unroll
  for (int qi = 0; qi < 2; ++qi)
    #pragma unroll
    for (int kq = 0; kq < 4; ++kq)
      qf[qi][kq] = *(const bf16x8*)(qp + (size_t)(qi * 16 + l16) * D_ + kq * 32 + g4 * 8);

  f32x4 o[2][8] = {};
  float l_part[2] = {0.f, 0.f};

  // prologue: stage tile 0 into buf 0
  {
    #pragma unroll
    for (int j = 0; j < 4; ++j) {
      int key = w * 16 + j * 4 + kr4;
      int cg = kc ^ (key & 7);
      gl16(kp + (size_t)key * D_ + cg * 8, &Ks[0][(w * 16 + j * 4) * D_]);
    }
    #pragma unroll
    for (int j = 0; j < 4; ++j) {
      int d = w * 32 + j * 8 + vr8;
      int cg = vc ^ (d & 7);
      gl16(vp + (size_t)d * T_ + cg * 8, &Vs[0][(w * 32 + j * 8) * KVB]);
    }
  }

  for (int t = 0; t < nt; ++t) {
    __syncthreads();   // drains vmcnt(0): buf[t&1] staged; prev compute done
    if (t + 1 < nt) {  // stage next tile into other buffer
      const int kv1 = (t + 1) * KVB;
      #pragma unroll
      for (int j = 0; j < 4; ++j) {
        int key = w * 16 + j * 4 + kr4;
        int cg = kc ^ (key & 7);
        gl16(kp + (size_t)(kv1 + key) * D_ + cg * 8, &Ks[(t + 1) & 1][(w * 16 + j * 4) * D_]);
      }
      #pragma unroll
      for (int j = 0; j < 4; ++j) {
        int d = w * 32 + j * 8 + vr8;
        int cg = vc ^ (d & 7);
        gl16(vp + (size_t)d * T_ + kv1 + cg * 8, &Vs[(t + 1) & 1][(w * 32 + j * 8) * KVB]);
      }
    }
    const int kv0 = t * KVB;
    if (kv0 <= qmax) {
      const unsigned short* kb = Ks[t & 1];
      const unsigned short* vb = Vs[t & 1];
      // S^T[key][q] = sum_d K[key][d]*Q[q][d]
      f32x4 sacc[2][4] = {};
      #pragma unroll
      for (int ss = 0; ss < 4; ++ss) {
        const int key = ss * 16 + l16;
        bf16x8 kf[4];
        #pragma unroll
        for (int kq = 0; kq < 4; ++kq) {
          int sc = (kq * 4 + g4) ^ (key & 7);
          kf[kq] = *(const bf16x8*)(kb + key * D_ + sc * 8);
        }
        #pragma unroll
        for (int qi = 0; qi < 2; ++qi)
          #pragma unroll
          for (int kq = 0; kq < 4; ++kq)
            sacc[qi][ss] = __builtin_amdgcn_mfma_f32_16x16x32_bf16(
                kf[kq], qf[qi][kq], sacc[qi][ss], 0, 0, 0);
      }
      const bool need_mask = (kv0 + KVB - 1 > qrow0);
      bf16x8 pf[2][2];
      #pragma unroll
      for (int qi = 0; qi < 2; ++qi) {
        const int qglob = qrow0 + qi * 16 + l16;
        float p[16];
        float ls = 0.f;
        #pragma unroll
        for (int ss = 0; ss < 4; ++ss) {
          #pragma unroll
          for (int r = 0; r < 4; ++r) {
            float e = EXP2(sacc[qi][ss][r]);   // bounded: |arg| <= 16.33
            if (need_mask) {
              int key = kv0 + ss * 16 + g4 * 4 + r;
              e = (key <= qglob) ? e : 0.f;
            }
            p[ss * 4 + r] = e;
            ls += e;
          }
        }
        l_part[qi] += ls;
        // P[q][key] -> per-wave LDS (swizzled 16B chunks), then immediate
        // cross-lane readback for this qi (buffer reused by next qi; the
        // compiler orders the wave-wide RAW/WAR through lgkmcnt)
        #pragma unroll
        for (int ss = 0; ss < 4; ++ss) {
          uint2 u;
          u.x = cvtpk(p[ss * 4 + 0], p[ss * 4 + 1]);
          u.y = cvtpk(p[ss * 4 + 2], p[ss * 4 + 3]);
          int ch = ss * 2 + (g4 >> 1);
          int sc = ch ^ (l16 & 7);
          *(uint2*)&pw[l16 * 64 + sc * 8 + (g4 & 1) * 4] = u;
        }
        #pragma unroll
        for (int ks = 0; ks < 2; ++ks) {
          int sc = (ks * 4 + g4) ^ (l16 & 7);
          pf[qi][ks] = *(const bf16x8*)&pw[l16 * 64 + sc * 8];
        }
      }
      // PV: O^T[d][q] += sum_key V^T[d][key] * P[q][key]
      #pragma unroll
      for (int dt = 0; dt < 8; ++dt) {
        const int d = dt * 16 + l16;
        int sc0 = (0 * 4 + g4) ^ (d & 7);
        int sc1 = (1 * 4 + g4) ^ (d & 7);
        bf16x8 vf0 = *(const bf16x8*)(vb + d * KVB + sc0 * 8);
        bf16x8 vf1 = *(const bf16x8*)(vb + d * KVB + sc1 * 8);
        #pragma unroll
        for (int qi = 0; qi < 2; ++qi) {
          o[qi][dt] = __builtin_amdgcn_mfma_f32_16x16x32_bf16(vf0, pf[qi][0], o[qi][dt], 0, 0, 0);
          o[qi][dt] = __builtin_amdgcn_mfma_f32_16x16x32_bf16(vf1, pf[qi][1], o[qi][dt], 0, 0, 0);
        }
      }
    }
  }

  #pragma unroll
  for (int qi = 0; qi < 2; ++qi) {
    float lsum = l_part[qi];
    lsum += __shfl_xor(lsum, 16);
    lsum += __shfl_xor(lsum, 32);
    const float inv_l = 1.0f / lsum;
    unsigned short* yrow = Yb + ((size_t)(b * T_ + qrow0 + qi * 16 + l16) * CEMB) + h * D_;
    #pragma unroll
    for (int dt = 0; dt < 8; ++dt) {
      uint2 u;
      u.x = cvtpk(o[qi][dt][0] * inv_l, o[qi][dt][1] * inv_l);
      u.y = cvtpk(o[qi][dt][2] * inv_l, o[qi][dt][3] * inv_l);
      *(uint2*)(yrow + dt * 16 + g4 * 4) = u;
    }
  }
}

// ---------------------------------------------------------------------------
extern "C" void kernel_launch(void* const* d_in, const int* in_sizes, int n_in,
                              void* d_out, int out_size, void* d_ws, size_t ws_size,
                              hipStream_t stream) {
  const float* x    = (const float*)d_in[0];
  const float* cosp = (const float*)d_in[1];
  const float* sinp = (const float*)d_in[2];
  const float* Wq   = (const float*)d_in[3];
  const float* Wk   = (const float*)d_in[4];
  const float* Wv   = (const float*)d_in[5];
  const float* Wo   = (const float*)d_in[6];
  float* out = (float*)d_out;

  char* ws = (char*)d_ws;
  size_t off = 0;
  auto alloc = [&](size_t bytes) {
    void* p = ws + off;
    off += (bytes + 255) & ~(size_t)255;
    return p;
  };
  const size_t MT = (size_t)B_ * T_;  // 4096
  const int NQKV = 3072;              // 2048 q + 512 k + 512 v
  unsigned short* xb    = (unsigned short*)alloc(MT * CEMB * 2);
  unsigned short* wqkvb = (unsigned short*)alloc((size_t)NQKV * 2048 * 2);
  unsigned short* wob   = (unsigned short*)alloc((size_t)2048 * 2048 * 2);
  unsigned short* qkvb  = (unsigned short*)alloc(MT * NQKV * 2);
  unsigned short* qn    = (unsigned short*)alloc((size_t)B_ * H_ * T_ * D_ * 2);
  unsigned short* kn    = (unsigned short*)alloc((size_t)B_ * HKV_ * T_ * D_ * 2);
  unsigned short* vt    = (unsigned short*)alloc((size_t)B_ * HKV_ * D_ * T_ * 2);
  unsigned short* yb    = (unsigned short*)alloc(MT * CEMB * 2);

  // bf16 casts (weights concatenated into [3072][2048])
  cvt_kernel<<<2048, 256, 0, stream>>>(x,  xb, (int)(MT * CEMB / 4));
  cvt_kernel<<<1024, 256, 0, stream>>>(Wq, wqkvb,                2048 * 2048 / 4);
  cvt_kernel<<<256,  256, 0, stream>>>(Wk, wqkvb + 2048 * 2048,  512 * 2048 / 4);
  cvt_kernel<<<256,  256, 0, stream>>>(Wv, wqkvb + 2560 * 2048,  512 * 2048 / 4);
  cvt_kernel<<<1024, 256, 0, stream>>>(Wo, wob,                  2048 * 2048 / 4);

  // fused QKV projection: [4096][3072] bf16  (grid 12x16 = 192 blocks)
  gemm256<<<dim3(NQKV / 256, 4096 / 256), 512, 0, stream>>>(xb, wqkvb, qkvb, 4096, NQKV, 2048, 1);

  // RoPE + RMSNorm; Q gets (1/sqrt(D))*log2(e) folded (softmax in exp2 domain)
  rope_norm<<<4096 * H_,   128, 0, stream>>>(qkvb,        NQKV, cosp, sinp, qn, H_,   0.1275174324f);
  rope_norm<<<4096 * HKV_, 128, 0, stream>>>(qkvb + 2048, NQKV, cosp, sinp, kn, HKV_, 1.0f);
  vtrans<<<dim3(T_ / 64, D_ / 32, B_ * HKV_), 256, 0, stream>>>(qkvb + 2560, NQKV, vt);

  // causal flash attention: 512 one-tile blocks, complementary halves, 2/CU
  attn_kernel<<<dim3(B_ * H_, 16), 256, 0, stream>>>(qn, kn, vt, yb);

  // output projection -> f32 d_out  (grid 8x16 = 128 blocks)
  gemm256<<<dim3(2048 / 256, 4096 / 256), 512, 0, stream>>>(yb, wob, out, 4096, 2048, 2048, 0);
}

// Round 7
// 248.250 us; speedup vs baseline: 1.0961x; 1.0318x over previous
//
#include <hip/hip_runtime.h>
#include <hip/hip_bf16.h>
#include <stdint.h>

#define B_   2
#define T_   2048
#define CEMB 2048
#define H_   16
#define HKV_ 4
#define D_   128

typedef __attribute__((ext_vector_type(8))) short bf16x8;    // 8 x bf16 (4 VGPR)
typedef __attribute__((ext_vector_type(4))) float f32x4;     // 16x16 MFMA acc
typedef __attribute__((ext_vector_type(16))) float f32x16;   // 32x32 MFMA acc

#if __has_builtin(__builtin_amdgcn_exp2f)
#define EXP2(x) __builtin_amdgcn_exp2f(x)
#else
#define EXP2(x) exp2f(x)
#endif

__device__ __forceinline__ unsigned short f2b(float f) {
  union { float f; unsigned u; } v; v.f = f;
  unsigned r = v.u + 0x7FFFu + ((v.u >> 16) & 1u);   // RNE
  return (unsigned short)(r >> 16);
}
__device__ __forceinline__ float b2f(unsigned short u) {
  union { unsigned u; float f; } v; v.u = ((unsigned)u) << 16; return v.f;
}
// pack 2 f32 -> 2 bf16 (RNE), single instruction; src0 -> low half
__device__ __forceinline__ unsigned cvtpk(float lo, float hi) {
  unsigned r;
  asm("v_cvt_pk_bf16_f32 %0, %1, %2" : "=v"(r) : "v"(lo), "v"(hi));
  return r;
}

// async global->LDS, 16B per lane; LDS dest = wave-uniform base + lane*16
__device__ __forceinline__ void gl16(const void* g, void* l) {
  __builtin_amdgcn_global_load_lds(
      (const __attribute__((address_space(1))) unsigned int*)g,
      (__attribute__((address_space(3))) unsigned int*)l, 16, 0, 0);
}

#define FENCE() asm volatile("" ::: "memory")

// ---------------- f32 -> bf16 convert (vectorized) ----------------
__global__ void cvt_kernel(const float* __restrict__ src,
                           unsigned short* __restrict__ dst, int n4) {
  int i = blockIdx.x * blockDim.x + threadIdx.x;
  const int stride = gridDim.x * blockDim.x;
  for (; i < n4; i += stride) {
    float4 v = ((const float4*)src)[i];
    ushort4 o;
    o.x = f2b(v.x); o.y = f2b(v.y); o.z = f2b(v.z); o.w = f2b(v.w);
    ((ushort4*)dst)[i] = o;
  }
}

// ---------------- GEMM 256x256, 8-phase counted-vmcnt pipeline ---------------
__global__ __launch_bounds__(512, 2)
void gemm256(const unsigned short* __restrict__ A,
             const unsigned short* __restrict__ W,
             void* __restrict__ Cmat, int M, int N, int K, int obf16) {
  __shared__ alignas(16) unsigned short As[2][2][128][64];
  __shared__ alignas(16) unsigned short Bs[2][2][128][64];

  const int tid  = threadIdx.x;
  const int lane = tid & 63;
  const int w    = tid >> 6;         // wave 0..7
  const int wr   = w >> 2;           // M interleave bit
  const int wc   = w & 3;            // N interleave
  const int l16  = lane & 15, g4 = lane >> 4;
  const int srow = lane >> 3;        // staging row within 8-row group
  const int schk = lane & 7;         // staging 16B chunk

  const int gx  = gridDim.x;
  const int nwg = gx * gridDim.y;
  const int lin = blockIdx.y * gx + blockIdx.x;
  const int cpx = nwg >> 3;
  const int swz = (lin & 7) * cpx + (lin >> 3);
  const int m0 = (swz / gx) * 256;
  const int n0 = (swz % gx) * 256;

  const unsigned short* Ap = A + (size_t)m0 * K;
  const unsigned short* Wp = W + (size_t)n0 * K;
  const int nk = K >> 6;

  f32x4 acc[8][4] = {};

  auto stA = [&](int ts, int h) {    // stage A half-tile (128 rows x 64 k)
    const unsigned short* g = Ap + (size_t)(h * 128 + w * 8 + srow) * K
                                 + ts * 64 + ((schk ^ srow) << 3);
    unsigned short* l = &As[ts & 1][h][w * 8][0];
    gl16(g, l);
    gl16(g + (size_t)64 * K, l + 64 * 64);
  };
  auto stB = [&](int ts, int h) {
    const unsigned short* g = Wp + (size_t)(h * 128 + w * 8 + srow) * K
                                 + ts * 64 + ((schk ^ srow) << 3);
    unsigned short* l = &Bs[ts & 1][h][w * 8][0];
    gl16(g, l);
    gl16(g + (size_t)64 * K, l + 64 * 64);
  };

  // prologue: stream halves 0..5 = tile0 {A0,B0,A1,B1} + tile1 {A0,B0}
  stA(0, 0); stB(0, 0); stA(0, 1); stB(0, 1);
  stA(1, 0); stB(1, 0);
  asm volatile("s_waitcnt vmcnt(4)" ::: "memory");   // tile0 fully landed
  __builtin_amdgcn_s_barrier();
  FENCE();

  for (int tau = 0; tau < nk; ++tau) {
    const int buf = tau & 1;
    #pragma unroll
    for (int ha = 0; ha < 2; ++ha) {
      // ===== phase P0 (quadrant ha,hb=0): load af[ha] (8) + bfr0 (4) =====
      bf16x8 af[4][2], bfr[2][2];
      #pragma unroll
      for (int mi = 0; mi < 4; ++mi) {
        const int har = (mi * 2 + wr) * 16 + l16;
        #pragma unroll
        for (int ks = 0; ks < 2; ++ks)
          af[mi][ks] = *(const bf16x8*)&As[buf][ha][har][((ks * 4 + g4) ^ (l16 & 7)) << 3];
      }
      #pragma unroll
      for (int ni = 0; ni < 2; ++ni) {
        const int hbr = (ni * 4 + wc) * 16 + l16;
        #pragma unroll
        for (int ks = 0; ks < 2; ++ks)
          bfr[ni][ks] = *(const bf16x8*)&Bs[buf][0][hbr][((ks * 4 + g4) ^ (l16 & 7)) << 3];
      }
      if (ha == 0) { if (tau + 1 < nk) stA(tau + 1, 1); }
      else         { if (tau + 2 < nk) stA(tau + 2, 0); }
      __builtin_amdgcn_s_barrier();
      asm volatile("s_waitcnt lgkmcnt(0)" ::: "memory");
      __builtin_amdgcn_s_setprio(1);
      #pragma unroll
      for (int mi = 0; mi < 4; ++mi) {
        #pragma unroll
        for (int ni = 0; ni < 2; ++ni) {
          f32x4 t = acc[ha * 4 + mi][ni];
          t = __builtin_amdgcn_mfma_f32_16x16x32_bf16(af[mi][0], bfr[ni][0], t, 0, 0, 0);
          t = __builtin_amdgcn_mfma_f32_16x16x32_bf16(af[mi][1], bfr[ni][1], t, 0, 0, 0);
          acc[ha * 4 + mi][ni] = t;
        }
      }
      __builtin_amdgcn_s_setprio(0);
      __builtin_amdgcn_s_barrier();
      FENCE();
      // ===== phase P1 (quadrant ha,hb=1): load bfr1 only (4); af reused =====
      #pragma unroll
      for (int ni = 0; ni < 2; ++ni) {
        const int hbr = (ni * 4 + wc) * 16 + l16;
        #pragma unroll
        for (int ks = 0; ks < 2; ++ks)
          bfr[ni][ks] = *(const bf16x8*)&Bs[buf][1][hbr][((ks * 4 + g4) ^ (l16 & 7)) << 3];
      }
      if (ha == 0) { if (tau + 1 < nk) stB(tau + 1, 1); }
      else         { if (tau + 2 < nk) stB(tau + 2, 0); }
      __builtin_amdgcn_s_barrier();
      asm volatile("s_waitcnt lgkmcnt(0)" ::: "memory");
      __builtin_amdgcn_s_setprio(1);
      #pragma unroll
      for (int mi = 0; mi < 4; ++mi) {
        #pragma unroll
        for (int ni = 0; ni < 2; ++ni) {
          f32x4 t = acc[ha * 4 + mi][2 + ni];
          t = __builtin_amdgcn_mfma_f32_16x16x32_bf16(af[mi][0], bfr[ni][0], t, 0, 0, 0);
          t = __builtin_amdgcn_mfma_f32_16x16x32_bf16(af[mi][1], bfr[ni][1], t, 0, 0, 0);
          acc[ha * 4 + mi][2 + ni] = t;
        }
      }
      __builtin_amdgcn_s_setprio(0);
      if (ha == 1) {   // K-tile gate: tile tau+1's 4 halves landed
        if (tau + 2 < nk) asm volatile("s_waitcnt vmcnt(4)" ::: "memory");
        else              asm volatile("s_waitcnt vmcnt(0)" ::: "memory");
      }
      __builtin_amdgcn_s_barrier();
      FENCE();
    }
  }

  #pragma unroll
  for (int fr = 0; fr < 8; ++fr) {
    #pragma unroll
    for (int fc = 0; fc < 4; ++fc) {
      const int row = m0 + (fr * 2 + wr) * 16 + g4 * 4;
      const int col = n0 + (fc * 4 + wc) * 16 + l16;
      if (obf16) {
        unsigned short* Cb = (unsigned short*)Cmat;
        #pragma unroll
        for (int r = 0; r < 4; ++r)
          Cb[(size_t)(row + r) * N + col] = f2b(acc[fr][fc][r]);
      } else {
        float* Cf = (float*)Cmat;
        #pragma unroll
        for (int r = 0; r < 4; ++r)
          Cf[(size_t)(row + r) * N + col] = acc[fr][fc][r];
      }
    }
  }
}

// ---------------- fused RoPE + RMSNorm (bf16 in) + [B,H,T,D] bf16 out --------
__global__ __launch_bounds__(128)
void rope_norm(const unsigned short* __restrict__ X, int rstride,
               const float* __restrict__ Cos, const float* __restrict__ Sin,
               unsigned short* __restrict__ Out, int Hn, float out_scale) {
  const int idx = blockIdx.x;
  const int h  = idx % Hn;
  const int bt = idx / Hn;
  const int t  = bt & (T_ - 1);
  const int b  = bt >> 11;
  const int d  = threadIdx.x;        // 0..127
  const unsigned short* src = X + (size_t)bt * rstride + h * D_;
  float y;
  if (d < 64) {
    float x1 = b2f(src[d]), x2 = b2f(src[d + 64]);
    float c = Cos[t * 64 + d], s = Sin[t * 64 + d];
    y = x1 * c + x2 * s;
  } else {
    int dd = d - 64;
    float x1 = b2f(src[dd]), x2 = b2f(src[d]);
    float c = Cos[t * 64 + dd], s = Sin[t * 64 + dd];
    y = -x1 * s + x2 * c;
  }
  float ss = y * y;
  #pragma unroll
  for (int m = 32; m; m >>= 1) ss += __shfl_xor(ss, m);
  __shared__ float red[2];
  if ((d & 63) == 0) red[d >> 6] = ss;
  __syncthreads();
  const float tot  = red[0] + red[1];
  const float rinv = rsqrtf(tot * (1.0f / 128.0f) + 1.1920929e-7f) * out_scale;
  Out[(((size_t)b * Hn + h) * T_ + t) * D_ + d] = f2b(y * rinv);
}

// ---------------- V: [B,T,*,D] bf16 (strided) -> [B,HKV,D,T] bf16 ------------
__global__ __launch_bounds__(256)
void vtrans(const unsigned short* __restrict__ Vf, int rstride,
            unsigned short* __restrict__ Vt) {
  __shared__ float tile[32][65];
  const int t0 = blockIdx.x * 64;
  const int d0 = blockIdx.y * 32;
  const int bh = blockIdx.z;
  const int b = bh >> 2, hk = bh & 3;
  const int tid = threadIdx.x;
  {
    const int di = tid & 31, ts = tid >> 5;
    #pragma unroll
    for (int i = 0; i < 8; ++i) {
      int tt = ts + i * 8;
      tile[di][tt] = b2f(Vf[(size_t)(b * T_ + t0 + tt) * rstride + hk * D_ + d0 + di]);
    }
  }
  __syncthreads();
  {
    const int ti = tid & 63, ds = tid >> 6;
    #pragma unroll
    for (int i = 0; i < 8; ++i) {
      int dd = ds * 8 + i;
      Vt[((size_t)bh * D_ + d0 + dd) * T_ + t0 + ti] = f2b(tile[dd][ti]);
    }
  }
}

// ---------------- flash attention, causal, 32x32 MFMA, in-register P ---------
// 4 waves x 32 q-rows; KVB=64 double-buffered in LDS (64 KB, no P scratch).
// Swapped QK^T (mfma(K,Q)) -> lane holds S^T[16 keys][q=lane&31] per 32-key
// block; softmax fully per-lane; P->PV A-frags via cvt_pk + shfl_xor(32).
// Fixed-shift softmax (RMSNorm bound |score*log2e| <= 16.33): P = exp2(S').
#define KVB 64

__global__ __launch_bounds__(256, 2)
void attn_kernel(const unsigned short* __restrict__ Qn,
                 const unsigned short* __restrict__ Kn,
                 const unsigned short* __restrict__ Vt,
                 unsigned short* __restrict__ Yb) {
  __shared__ alignas(16) unsigned short Ks[2][KVB * D_];   // [key][chunk^(key&7)]
  __shared__ alignas(16) unsigned short Vs[2][D_ * KVB];   // V^T [d][chunk^(d&7)]

  const int tid = threadIdx.x;
  const int lane = tid & 63;
  const int w = tid >> 6;
  const int l31 = lane & 31;
  const int hi  = lane >> 5;
  const int bh = blockIdx.x;
  const int by = blockIdx.y;
  const int qt = (by < 8) ? by : 23 - by; // complementary halves (c, c+256)
  const int b = bh >> 4, h = bh & 15;
  const int hk = h >> 2;                  // GQA: 4 q-heads per kv-head

  const unsigned short* kp = Kn + ((size_t)(b * HKV_ + hk) * T_) * D_;
  const unsigned short* vp = Vt + ((size_t)(b * HKV_ + hk) * D_) * T_;

  // staging lane decomposition
  const int kr4 = lane >> 4, kc = lane & 15;   // K: 4 rows (256B) per instr
  const int vr8 = lane >> 3, vc = lane & 7;    // V: 8 rows (128B) per instr

  const int t0 = qt * 128;
  const int qrow0 = t0 + w * 32;
  const int qmax = qrow0 + 31;
  const int nt = qt * 2 + 2;
  const int qglob = qrow0 + l31;

  // Q fragments: B-operand, col=q=lane&31, k-chunk = hi*8 (8 per d-step of 16)
  const unsigned short* qp = Qn + ((size_t)bh * T_ + qrow0) * D_;
  bf16x8 qf[8];
  #pragma unroll
  for (int ds = 0; ds < 8; ++ds)
    qf[ds] = *(const bf16x8*)(qp + (size_t)l31 * D_ + ds * 16 + hi * 8);

  f32x16 o[4] = {};        // o[db]: O[q=crow(r,hi)][d = db*32 + l31]
  float l_lane = 0.f;      // per-lane l for q = l31 (partner holds other half)

  // prologue: stage tile 0 into buf 0
  {
    #pragma unroll
    for (int j = 0; j < 4; ++j) {
      int key = w * 16 + j * 4 + kr4;
      int cg = kc ^ (key & 7);
      gl16(kp + (size_t)key * D_ + cg * 8, &Ks[0][(w * 16 + j * 4) * D_]);
    }
    #pragma unroll
    for (int j = 0; j < 4; ++j) {
      int d = w * 32 + j * 8 + vr8;
      int cg = vc ^ (d & 7);
      gl16(vp + (size_t)d * T_ + cg * 8, &Vs[0][(w * 32 + j * 8) * KVB]);
    }
  }

  union PAu { unsigned u[4]; bf16x8 v; };

  for (int t = 0; t < nt; ++t) {
    __syncthreads();   // drains vmcnt(0): buf[t&1] staged; prev compute done
    if (t + 1 < nt) {  // stage next tile into other buffer
      const int kv1 = (t + 1) * KVB;
      #pragma unroll
      for (int j = 0; j < 4; ++j) {
        int key = w * 16 + j * 4 + kr4;
        int cg = kc ^ (key & 7);
        gl16(kp + (size_t)(kv1 + key) * D_ + cg * 8, &Ks[(t + 1) & 1][(w * 16 + j * 4) * D_]);
      }
      #pragma unroll
      for (int j = 0; j < 4; ++j) {
        int d = w * 32 + j * 8 + vr8;
        int cg = vc ^ (d & 7);
        gl16(vp + (size_t)d * T_ + kv1 + cg * 8, &Vs[(t + 1) & 1][(w * 32 + j * 8) * KVB]);
      }
    }
    const int kv0 = t * KVB;
    if (kv0 <= qmax) {
      const unsigned short* kb = Ks[t & 1];
      const unsigned short* vb = Vs[t & 1];
      // ---- QK^T swapped: sacc[kb] = sum_ds mfma32(K_frag, Q_frag) ----
      f32x16 s0 = {}, s1 = {};
      #pragma unroll
      for (int ds = 0; ds < 8; ++ds) {
        const int c = (ds * 2 + hi) ^ (l31 & 7);
        bf16x8 k0 = *(const bf16x8*)(kb + (size_t)l31 * D_ + c * 8);
        bf16x8 k1 = *(const bf16x8*)(kb + (size_t)(32 + l31) * D_ + c * 8);
        s0 = __builtin_amdgcn_mfma_f32_32x32x16_bf16(k0, qf[ds], s0, 0, 0, 0);
        s1 = __builtin_amdgcn_mfma_f32_32x32x16_bf16(k1, qf[ds], s1, 0, 0, 0);
      }
      // ---- softmax (fixed-shift, exp2 domain), per-lane ----
      const bool need_mask = (kv0 + KVB - 1 > qrow0);
      float e0[16], e1[16];
      float ls = 0.f;
      #pragma unroll
      for (int r = 0; r < 16; ++r) {
        const int crow = (r & 3) + 8 * (r >> 2) + 4 * hi;
        float v0 = EXP2(s0[r]);
        float v1 = EXP2(s1[r]);
        if (need_mask) {
          v0 = (kv0 + crow      <= qglob) ? v0 : 0.f;
          v1 = (kv0 + 32 + crow <= qglob) ? v1 : 0.f;
        }
        e0[r] = v0; e1[r] = v1;
        ls += v0 + v1;
      }
      l_lane += ls;
      // ---- build PV A-fragments in-register (cvt_pk + shfl_xor 32) ----
      PAu pa[4];
      {
        unsigned a0 = cvtpk(e0[0],  e0[1]),  a1 = cvtpk(e0[2],  e0[3]);
        unsigned b0 = cvtpk(e0[4],  e0[5]),  b1 = cvtpk(e0[6],  e0[7]);
        unsigned c0 = cvtpk(e0[8],  e0[9]),  c1 = cvtpk(e0[10], e0[11]);
        unsigned d0 = cvtpk(e0[12], e0[13]), d1 = cvtpk(e0[14], e0[15]);
        unsigned sa0 = __shfl_xor(a0, 32), sa1 = __shfl_xor(a1, 32);
        unsigned sb0 = __shfl_xor(b0, 32), sb1 = __shfl_xor(b1, 32);
        unsigned sc0 = __shfl_xor(c0, 32), sc1 = __shfl_xor(c1, 32);
        unsigned sd0 = __shfl_xor(d0, 32), sd1 = __shfl_xor(d1, 32);
        pa[0].u[0] = hi ? sb0 : a0;  pa[0].u[1] = hi ? sb1 : a1;
        pa[0].u[2] = hi ? b0  : sa0; pa[0].u[3] = hi ? b1  : sa1;
        pa[1].u[0] = hi ? sd0 : c0;  pa[1].u[1] = hi ? sd1 : c1;
        pa[1].u[2] = hi ? d0  : sc0; pa[1].u[3] = hi ? d1  : sc1;
      }
      {
        unsigned a0 = cvtpk(e1[0],  e1[1]),  a1 = cvtpk(e1[2],  e1[3]);
        unsigned b0 = cvtpk(e1[4],  e1[5]),  b1 = cvtpk(e1[6],  e1[7]);
        unsigned c0 = cvtpk(e1[8],  e1[9]),  c1 = cvtpk(e1[10], e1[11]);
        unsigned d0 = cvtpk(e1[12], e1[13]), d1 = cvtpk(e1[14], e1[15]);
        unsigned sa0 = __shfl_xor(a0, 32), sa1 = __shfl_xor(a1, 32);
        unsigned sb0 = __shfl_xor(b0, 32), sb1 = __shfl_xor(b1, 32);
        unsigned sc0 = __shfl_xor(c0, 32), sc1 = __shfl_xor(c1, 32);
        unsigned sd0 = __shfl_xor(d0, 32), sd1 = __shfl_xor(d1, 32);
        pa[2].u[0] = hi ? sb0 : a0;  pa[2].u[1] = hi ? sb1 : a1;
        pa[2].u[2] = hi ? b0  : sa0; pa[2].u[3] = hi ? b1  : sa1;
        pa[3].u[0] = hi ? sd0 : c0;  pa[3].u[1] = hi ? sd1 : c1;
        pa[3].u[2] = hi ? d0  : sc0; pa[3].u[3] = hi ? d1  : sc1;
      }
      // ---- PV: O[q][d] += P[q][key] * V[key][d], V as B-frag from V^T ----
      #pragma unroll
      for (int ks = 0; ks < 4; ++ks) {
        #pragma unroll
        for (int db = 0; db < 4; ++db) {
          const int d = db * 32 + l31;
          const int c = (ks * 2 + hi) ^ (d & 7);
          bf16x8 vf = *(const bf16x8*)(vb + (size_t)d * KVB + c * 8);
          o[db] = __builtin_amdgcn_mfma_f32_32x32x16_bf16(pa[ks].v, vf, o[db], 0, 0, 0);
        }
      }
    }
  }

  // ---- epilogue: l broadcast per output row, scaled bf16 store ----
  const float lfull = l_lane + __shfl_xor(l_lane, 32);
  const float invq = 1.0f / lfull;     // valid for q = l31 on this lane
  #pragma unroll
  for (int r = 0; r < 16; ++r) {
    const int crow = (r & 3) + 8 * (r >> 2) + 4 * hi;
    const float inv = __shfl(invq, crow);   // l for row q=crow (lanes 0..31 hold all q)
    unsigned short* yrow = Yb + ((size_t)(b * T_ + qrow0 + crow) * CEMB) + h * D_;
    #pragma unroll
    for (int db = 0; db < 4; ++db)
      yrow[db * 32 + l31] = f2b(o[db][r] * inv);
  }
}

// ---------------------------------------------------------------------------
extern "C" void kernel_launch(void* const* d_in, const int* in_sizes, int n_in,
                              void* d_out, int out_size, void* d_ws, size_t ws_size,
                              hipStream_t stream) {
  const float* x    = (const float*)d_in[0];
  const float* cosp = (const float*)d_in[1];
  const float* sinp = (const float*)d_in[2];
  const float* Wq   = (const float*)d_in[3];
  const float* Wk   = (const float*)d_in[4];
  const float* Wv   = (const float*)d_in[5];
  const float* Wo   = (const float*)d_in[6];
  float* out = (float*)d_out;

  char* ws = (char*)d_ws;
  size_t off = 0;
  auto alloc = [&](size_t bytes) {
    void* p = ws + off;
    off += (bytes + 255) & ~(size_t)255;
    return p;
  };
  const size_t MT = (size_t)B_ * T_;  // 4096
  const int NQKV = 3072;              // 2048 q + 512 k + 512 v
  unsigned short* xb    = (unsigned short*)alloc(MT * CEMB * 2);
  unsigned short* wqkvb = (unsigned short*)alloc((size_t)NQKV * 2048 * 2);
  unsigned short* wob   = (unsigned short*)alloc((size_t)2048 * 2048 * 2);
  unsigned short* qkvb  = (unsigned short*)alloc(MT * NQKV * 2);
  unsigned short* qn    = (unsigned short*)alloc((size_t)B_ * H_ * T_ * D_ * 2);
  unsigned short* kn    = (unsigned short*)alloc((size_t)B_ * HKV_ * T_ * D_ * 2);
  unsigned short* vt    = (unsigned short*)alloc((size_t)B_ * HKV_ * D_ * T_ * 2);
  unsigned short* yb    = (unsigned short*)alloc(MT * CEMB * 2);

  // bf16 casts (weights concatenated into [3072][2048])
  cvt_kernel<<<2048, 256, 0, stream>>>(x,  xb, (int)(MT * CEMB / 4));
  cvt_kernel<<<1024, 256, 0, stream>>>(Wq, wqkvb,                2048 * 2048 / 4);
  cvt_kernel<<<256,  256, 0, stream>>>(Wk, wqkvb + 2048 * 2048,  512 * 2048 / 4);
  cvt_kernel<<<256,  256, 0, stream>>>(Wv, wqkvb + 2560 * 2048,  512 * 2048 / 4);
  cvt_kernel<<<1024, 256, 0, stream>>>(Wo, wob,                  2048 * 2048 / 4);

  // fused QKV projection: [4096][3072] bf16  (grid 12x16 = 192 blocks)
  gemm256<<<dim3(NQKV / 256, 4096 / 256), 512, 0, stream>>>(xb, wqkvb, qkvb, 4096, NQKV, 2048, 1);

  // RoPE + RMSNorm; Q gets (1/sqrt(D))*log2(e) folded (softmax in exp2 domain)
  rope_norm<<<4096 * H_,   128, 0, stream>>>(qkvb,        NQKV, cosp, sinp, qn, H_,   0.1275174324f);
  rope_norm<<<4096 * HKV_, 128, 0, stream>>>(qkvb + 2048, NQKV, cosp, sinp, kn, HKV_, 1.0f);
  vtrans<<<dim3(T_ / 64, D_ / 32, B_ * HKV_), 256, 0, stream>>>(qkvb + 2560, NQKV, vt);

  // causal flash attention: 512 one-tile blocks, complementary halves
  attn_kernel<<<dim3(B_ * H_, 16), 256, 0, stream>>>(qn, kn, vt, yb);

  // output projection -> f32 d_out  (grid 8x16 = 128 blocks)
  gemm256<<<dim3(2048 / 256, 4096 / 256), 512, 0, stream>>>(yb, wob, out, 4096, 2048, 2048, 0);
}